// Round 11
// baseline (305.933 us; speedup 1.0000x reference)
//
#include <hip/hip_runtime.h>
#include <float.h>

// Quantize: z [8,4096,512] f32, embed_w [512,128] f32, GROUPS=4
// flat = z.reshape(131072,128); dist to 512 codes; argmin; gather; MSE scalar.
// d_out (f32): z_q_st [16777216], diff [1], ind [131072] (as float).
//
// r11 = r6/r10 numerics at MAX occupancy (32 waves/CU):
//  - 4-wave blocks (256 thr), 128 rows, 1024 blocks, <=20KB LDS, <=64 VGPR
//    => 8 blocks/CU co-resident, phases interleave across blocks
//  - codebook scanned in EIGHT 16 KB passes (64 codes each), fp16-hi,
//    pre-swizzled Wp DMA'd via global_load_lds (linear dest)
//  - rows with top-2 score margin < TAU_A re-solved EXACTLY in fp64
//    (fp64 dot + fp64 ||w||^2, block-distributed worklist) => exact indices

typedef _Float16 half8 __attribute__((ext_vector_type(8)));
typedef __attribute__((ext_vector_type(4))) float f32x4;

constexpr int Dn = 128;
constexpr int K  = 512;
constexpr long long Mrows = 131072;
constexpr int RPW   = 32;                    // rows per wave
constexpr int WAVES = 4;                     // waves per block (256 threads)
constexpr int RPB   = RPW * WAVES;           // 128 rows per block
constexpr int NBLK  = (int)(Mrows / RPB);    // 1024
constexpr int KCH   = 64;                    // codes per pass (16 KB fp16)
constexpr int NPASS = K / KCH;               // 8
constexpr float TAU_A = 0.05f;               // score-margin for exact re-solve

constexpr size_t ZQ_SIZE  = (size_t)Mrows * Dn;
constexpr size_t DIFF_OFF = ZQ_SIZE;
constexpr size_t IND_OFF  = ZQ_SIZE + 1;

__device__ inline void gload_lds16(const void* g, void* l) {
    __builtin_amdgcn_global_load_lds(
        (const __attribute__((address_space(1))) unsigned int*)g,
        (__attribute__((address_space(3))) unsigned int*)l,
        16, 0, 0);
}

// W -> fp16 hi, XOR-swizzled granule order (granule g of code stored at slot
// g ^ (code&7)); also wn2 = -0.5*||w||^2 (f32) and wn64 = ||w||^2 (f64).
__global__ void prep_kernel(const float* __restrict__ W,
                            unsigned short* __restrict__ Wp,
                            float* __restrict__ wn2,
                            double* __restrict__ wn64) {
    int t = blockIdx.x * 256 + threadIdx.x;  // 0..8191 (512 codes * 16 granules)
    int code = t >> 4;
    int g    = t & 15;
    const float* src = W + (size_t)code * Dn + g * 8;
    float4 a = *(const float4*)src;
    float4 b = *(const float4*)(src + 4);
    float vv[8] = {a.x, a.y, a.z, a.w, b.x, b.y, b.z, b.w};
    half8 hv;
    double s2 = 0.0;
    #pragma unroll
    for (int j = 0; j < 8; ++j) {
        hv[j] = (_Float16)vv[j];
        s2 += (double)vv[j] * (double)vv[j];
    }
    *(half8*)((char*)Wp + (size_t)code * 256 + ((g ^ (code & 7)) << 4)) = hv;
    s2 += __shfl_xor(s2, 1);
    s2 += __shfl_xor(s2, 2);
    s2 += __shfl_xor(s2, 4);
    s2 += __shfl_xor(s2, 8);
    if (g == 0) {
        wn2[code]  = (float)(-0.5 * s2);
        wn64[code] = s2;
    }
}

__global__ __launch_bounds__(256, 8) void vq_main(
        const float* __restrict__ Z, const float* __restrict__ W,
        const unsigned short* __restrict__ Wp, const float* __restrict__ wn2,
        const double* __restrict__ wn64,
        float* __restrict__ out, double* __restrict__ diffsum) {
    __shared__ __align__(16) char Wbuf[KCH * 256];   // 16 KB: one codebook pass
    __shared__ float wn2_s[K];                       // 2 KB
    __shared__ float xn_s[RPB];                      // 0.5 KB
    __shared__ int   sIdx[RPB];
    __shared__ int   flagList[RPB];
    __shared__ int   flagN;
    __shared__ float wpart[WAVES];

    const int tid  = threadIdx.x;
    const int w    = tid >> 6;
    const int lane = tid & 63;
    const int lm   = lane & 15;        // A row / B col within 16-tile
    const int lg   = lane >> 4;        // k-block (0..3)
    const size_t row0 = (size_t)blockIdx.x * RPB;

    if (tid == 0) flagN = 0;

    // ---- stage: DMA one 16 KB codebook pass into LDS (linear dest) ----
    auto stage = [&](int p) {
        const char* gsrc = (const char*)Wp + (size_t)p * (KCH * 256);
        #pragma unroll
        for (int it = 0; it < 4; ++it) {
            const int gbase = it * 256 + w * 64;             // wave-uniform base
            gload_lds16(gsrc + (size_t)(gbase + lane) * 16, Wbuf + (size_t)gbase * 16);
        }
    };
    stage(0);                           // issue pass-0 DMA first

    // ---- X fragments (fp16) + exact row norms (overlap the DMA) ----
    half8 ah[2][4];                     // [16-row tile][ks]
    #pragma unroll
    for (int r = 0; r < 2; ++r) {
        const size_t grow = row0 + (size_t)w * RPW + r * 16 + lm;
        float s2 = 0.f;
        #pragma unroll
        for (int ks = 0; ks < 4; ++ks) {
            const float* xp = Z + grow * Dn + ks * 32 + lg * 8;
            float4 x0 = *(const float4*)xp;
            float4 x1 = *(const float4*)(xp + 4);
            float xv[8] = {x0.x, x0.y, x0.z, x0.w, x1.x, x1.y, x1.z, x1.w};
            #pragma unroll
            for (int j = 0; j < 8; ++j) {
                ah[r][ks][j] = (_Float16)xv[j];
                s2 += xv[j] * xv[j];
            }
        }
        s2 += __shfl_xor(s2, 16);
        s2 += __shfl_xor(s2, 32);      // full ||x||^2 for row grow
        if (lg == 0) xn_s[w * RPW + r * 16 + lm] = s2;
    }
    #pragma unroll
    for (int i = 0; i < K / 256; ++i) wn2_s[tid + i * 256] = wn2[tid + i * 256];

    float m1[2][4], m2[2][4];
    int   i1[2][4];
    #pragma unroll
    for (int r = 0; r < 2; ++r)
        #pragma unroll
        for (int j = 0; j < 4; ++j) { m1[r][j] = -FLT_MAX; m2[r][j] = -FLT_MAX; i1[r][j] = 0; }

    asm volatile("s_waitcnt vmcnt(0)" ::: "memory");
    __syncthreads();                   // B1: pass-0 + wn2 + flagN=0 resident

    // ---- 8-pass scan: 4 B-tiles per pass, fold carries across passes ----
    for (int p = 0; p < NPASS; ++p) {
        const int cbase = p * KCH;
        #pragma unroll
        for (int t = 0; t < 4; ++t) {
            const int code_l = t * 16 + lm;            // slot within Wbuf
            const int code   = cbase + code_l;
            const float cinit = wn2_s[code];
            half8 bh[4];
            #pragma unroll
            for (int ks = 0; ks < 4; ++ks) {
                const int off = code_l * 256 + ((((ks << 2) + lg) ^ (code_l & 7)) << 4);
                bh[ks] = *(const half8*)(Wbuf + off);
            }
            f32x4 acc[2];
            #pragma unroll
            for (int r = 0; r < 2; ++r) acc[r] = (f32x4){cinit, cinit, cinit, cinit};
            #pragma unroll
            for (int ks = 0; ks < 4; ++ks) {
                #pragma unroll
                for (int r = 0; r < 2; ++r)
                    acc[r] = __builtin_amdgcn_mfma_f32_16x16x32_f16(ah[r][ks], bh[ks], acc[r], 0, 0, 0);
            }
            #pragma unroll
            for (int r = 0; r < 2; ++r) {
                #pragma unroll
                for (int j = 0; j < 4; ++j) {
                    const float a = acc[r][j];
                    m2[r][j] = __builtin_amdgcn_fmed3f(a, m1[r][j], m2[r][j]);
                    const bool gt = a > m1[r][j];
                    m1[r][j] = fmaxf(m1[r][j], a);
                    i1[r][j] = gt ? code : i1[r][j];
                }
            }
        }
        if (p + 1 < NPASS) {
            __syncthreads();           // all waves done reading this pass
            stage(p + 1);              // DMA next 16 KB over the same buffer
            asm volatile("s_waitcnt vmcnt(0)" ::: "memory");
            __syncthreads();           // next pass resident
        }
    }

    // ---- reduce (m1, idx, m2) across the 16 col-lanes (wave-local) ----
    #pragma unroll
    for (int sft = 1; sft < 16; sft <<= 1) {
        #pragma unroll
        for (int r = 0; r < 2; ++r) {
            #pragma unroll
            for (int j = 0; j < 4; ++j) {
                float o1 = __shfl_xor(m1[r][j], sft);
                float o2 = __shfl_xor(m2[r][j], sft);
                int   oi = __shfl_xor(i1[r][j], sft);
                if (o1 > m1[r][j] || (o1 == m1[r][j] && oi < i1[r][j])) {
                    m2[r][j] = fmaxf(m1[r][j], o2);
                    m1[r][j] = o1;
                    i1[r][j] = oi;
                } else {
                    m2[r][j] = fmaxf(m2[r][j], o1);
                }
            }
        }
    }

    float psum = 0.f;
    if (lm == 0) {
        #pragma unroll
        for (int r = 0; r < 2; ++r) {
            #pragma unroll
            for (int j = 0; j < 4; ++j) {
                const int row = w * RPW + r * 16 + lg * 4 + j;   // C row = lg*4 + reg
                sIdx[row] = i1[r][j];
                psum += xn_s[row] - 2.f * m1[r][j];              // dist^2 = ||x||^2 - 2a
                if (m1[r][j] - m2[r][j] < TAU_A) {
                    int pos = atomicAdd(&flagN, 1);
                    flagList[pos] = row;
                }
            }
        }
    }
    __syncthreads();                   // B2: sIdx + worklist complete

    // ---- exact refinement, block-distributed over the worklist ----
    {
        const int nf = flagN;
        const int cg    = lane >> 3;           // code subgroup 0..7
        const int dbase = (lane & 7) * 16;     // 16-dim slice per lane
        for (int fi = w; fi < nf; fi += WAVES) {
            const int rr = flagList[fi];
            const float* xp = Z + (row0 + rr) * Dn + dbase;
            double xd[16];
            #pragma unroll
            for (int q = 0; q < 16; q += 4) {
                float4 v = *(const float4*)(xp + q);
                xd[q] = v.x; xd[q+1] = v.y; xd[q+2] = v.z; xd[q+3] = v.w;
            }
            double best = 1e300; int bi = 0;
            for (int cb = 0; cb < 64; ++cb) {
                const int c = cb * 8 + cg;
                const float* wp = W + (size_t)c * Dn + dbase;
                double s = 0.0;
                #pragma unroll
                for (int q = 0; q < 16; q += 4) {
                    float4 wv = *(const float4*)(wp + q);
                    s += xd[q]   * (double)wv.x;
                    s += xd[q+1] * (double)wv.y;
                    s += xd[q+2] * (double)wv.z;
                    s += xd[q+3] * (double)wv.w;
                }
                s += __shfl_xor(s, 1);
                s += __shfl_xor(s, 2);
                s += __shfl_xor(s, 4);         // all 8 lanes of group hold dot(c)
                const double sc = wn64[c] - 2.0 * s;   // dist^2 - ||x||^2 (exact)
                if (sc < best) { best = sc; bi = c; } // ascending c => min-idx tiebreak
            }
            #pragma unroll
            for (int sft = 8; sft < 64; sft <<= 1) {
                double ob = __shfl_xor(best, sft);
                int    ok = __shfl_xor(bi, sft);
                if (ob < best || (ob == best && ok < bi)) { best = ob; bi = ok; }
            }
            if (lane == 0) sIdx[rr] = bi;
        }
    }
    __syncthreads();                   // B3: refined sIdx visible

    // ---- epilogue: gather W[ind], store z_q_st, ind, diff ----
    #pragma unroll
    for (int it = 0; it < 16; ++it) {
        int f4i = lane + it * 64;              // 0..1023
        int rl  = f4i >> 5, cq = f4i & 31;     // 32 rows x 32 float4
        int ind = sIdx[w * RPW + rl];
        float4 wv = ((const float4*)(W + (size_t)ind * Dn))[cq];
        ((float4*)(out + (row0 + w * RPW + rl) * Dn))[cq] = wv;
    }
    if (lane < RPW)
        out[IND_OFF + row0 + w * RPW + lane] = (float)sIdx[w * RPW + lane];

    #pragma unroll
    for (int sft = 1; sft < 64; sft <<= 1) psum += __shfl_xor(psum, sft);
    if (lane == 0) wpart[w] = psum;
    __syncthreads();
    if (tid == 0) {
        double t = 0.0;
        #pragma unroll
        for (int i = 0; i < WAVES; ++i) t += (double)wpart[i];
        atomicAdd(diffsum, t);
    }
}

__global__ void diff_kernel(const double* __restrict__ diffsum, float* __restrict__ out) {
    if (threadIdx.x == 0 && blockIdx.x == 0) {
        // KLD_SCALE * (COMMITMENT_COST + 1) * mean = 12.5 * mean
        out[DIFF_OFF] = (float)(12.5 * diffsum[0] / (double)ZQ_SIZE);
    }
}

extern "C" void kernel_launch(void* const* d_in, const int* in_sizes, int n_in,
                              void* d_out, int out_size, void* d_ws, size_t ws_size,
                              hipStream_t stream) {
    (void)in_sizes; (void)n_in; (void)out_size; (void)ws_size;
    const float* Z = (const float*)d_in[0];
    const float* W = (const float*)d_in[1];
    float* out = (float*)d_out;
    // ws: [0,8) diffsum; [64,2112) wn2 f32[512]; [2112,6208) wn64 f64[512];
    //     [8192, +128KB) Wp fp16 swizzled
    double* diffsum = (double*)d_ws;
    float*  wn2  = (float*)((char*)d_ws + 64);
    double* wn64 = (double*)((char*)d_ws + 2112);
    unsigned short* Wp = (unsigned short*)((char*)d_ws + 8192);

    hipMemsetAsync(d_ws, 0, 16, stream);
    prep_kernel<<<32, 256, 0, stream>>>(W, Wp, wn2, wn64);
    vq_main<<<NBLK, 256, 0, stream>>>(Z, W, Wp, wn2, wn64, out, diffsum);
    diff_kernel<<<1, 64, 0, stream>>>(diffsum, out);
}

// Round 12
// 135.899 us; speedup vs baseline: 2.2512x; 2.2512x over previous
//
#include <hip/hip_runtime.h>
#include <float.h>

// Quantize: z [8,4096,512] f32, embed_w [512,128] f32, GROUPS=4
// flat = z.reshape(131072,128); dist to 512 codes; argmin; gather; MSE scalar.
// d_out (f32): z_q_st [16777216], diff [1], ind [131072] (as float).
//
// r12 = r11 structure with FIXED launch bounds: plain __launch_bounds__(256)
// (r11's (256,8) hint made the compiler allocate 32 VGPR -> massive spill).
// This inner structure compiles to ~60 VGPR naturally (r6/r7/r9), which at
// 20 KB LDS/block gives 8 blocks/CU = 32 waves/CU:
//  - 4-wave blocks (256 thr), 128 rows, 1024 blocks
//  - codebook scanned in EIGHT 16 KB passes (64 codes each), fp16-hi,
//    pre-swizzled Wp DMA'd via global_load_lds (linear dest)
//  - rows with top-2 score margin < TAU_A re-solved EXACTLY in fp64
//    (fp64 dot + fp64 ||w||^2, block-distributed worklist) => exact indices

typedef _Float16 half8 __attribute__((ext_vector_type(8)));
typedef __attribute__((ext_vector_type(4))) float f32x4;

constexpr int Dn = 128;
constexpr int K  = 512;
constexpr long long Mrows = 131072;
constexpr int RPW   = 32;                    // rows per wave
constexpr int WAVES = 4;                     // waves per block (256 threads)
constexpr int RPB   = RPW * WAVES;           // 128 rows per block
constexpr int NBLK  = (int)(Mrows / RPB);    // 1024
constexpr int KCH   = 64;                    // codes per pass (16 KB fp16)
constexpr int NPASS = K / KCH;               // 8
constexpr float TAU_A = 0.05f;               // score-margin for exact re-solve

constexpr size_t ZQ_SIZE  = (size_t)Mrows * Dn;
constexpr size_t DIFF_OFF = ZQ_SIZE;
constexpr size_t IND_OFF  = ZQ_SIZE + 1;

__device__ inline void gload_lds16(const void* g, void* l) {
    __builtin_amdgcn_global_load_lds(
        (const __attribute__((address_space(1))) unsigned int*)g,
        (__attribute__((address_space(3))) unsigned int*)l,
        16, 0, 0);
}

// W -> fp16 hi, XOR-swizzled granule order (granule g of code stored at slot
// g ^ (code&7)); also wn2 = -0.5*||w||^2 (f32) and wn64 = ||w||^2 (f64).
__global__ void prep_kernel(const float* __restrict__ W,
                            unsigned short* __restrict__ Wp,
                            float* __restrict__ wn2,
                            double* __restrict__ wn64) {
    int t = blockIdx.x * 256 + threadIdx.x;  // 0..8191 (512 codes * 16 granules)
    int code = t >> 4;
    int g    = t & 15;
    const float* src = W + (size_t)code * Dn + g * 8;
    float4 a = *(const float4*)src;
    float4 b = *(const float4*)(src + 4);
    float vv[8] = {a.x, a.y, a.z, a.w, b.x, b.y, b.z, b.w};
    half8 hv;
    double s2 = 0.0;
    #pragma unroll
    for (int j = 0; j < 8; ++j) {
        hv[j] = (_Float16)vv[j];
        s2 += (double)vv[j] * (double)vv[j];
    }
    *(half8*)((char*)Wp + (size_t)code * 256 + ((g ^ (code & 7)) << 4)) = hv;
    s2 += __shfl_xor(s2, 1);
    s2 += __shfl_xor(s2, 2);
    s2 += __shfl_xor(s2, 4);
    s2 += __shfl_xor(s2, 8);
    if (g == 0) {
        wn2[code]  = (float)(-0.5 * s2);
        wn64[code] = s2;
    }
}

__global__ __launch_bounds__(256) void vq_main(
        const float* __restrict__ Z, const float* __restrict__ W,
        const unsigned short* __restrict__ Wp, const float* __restrict__ wn2,
        const double* __restrict__ wn64,
        float* __restrict__ out, double* __restrict__ diffsum) {
    __shared__ __align__(16) char Wbuf[KCH * 256];   // 16 KB: one codebook pass
    __shared__ float wn2_s[K];                       // 2 KB
    __shared__ float xn_s[RPB];                      // 0.5 KB
    __shared__ int   sIdx[RPB];
    __shared__ int   flagList[RPB];
    __shared__ int   flagN;
    __shared__ float wpart[WAVES];

    const int tid  = threadIdx.x;
    const int w    = tid >> 6;
    const int lane = tid & 63;
    const int lm   = lane & 15;        // A row / B col within 16-tile
    const int lg   = lane >> 4;        // k-block (0..3)
    const size_t row0 = (size_t)blockIdx.x * RPB;

    if (tid == 0) flagN = 0;

    // ---- stage: DMA one 16 KB codebook pass into LDS (linear dest) ----
    auto stage = [&](int p) {
        const char* gsrc = (const char*)Wp + (size_t)p * (KCH * 256);
        #pragma unroll
        for (int it = 0; it < 4; ++it) {
            const int gbase = it * 256 + w * 64;             // wave-uniform base
            gload_lds16(gsrc + (size_t)(gbase + lane) * 16, Wbuf + (size_t)gbase * 16);
        }
    };
    stage(0);                           // issue pass-0 DMA first

    // ---- X fragments (fp16) + exact row norms (overlap the DMA) ----
    half8 ah[2][4];                     // [16-row tile][ks]
    #pragma unroll
    for (int r = 0; r < 2; ++r) {
        const size_t grow = row0 + (size_t)w * RPW + r * 16 + lm;
        float s2 = 0.f;
        #pragma unroll
        for (int ks = 0; ks < 4; ++ks) {
            const float* xp = Z + grow * Dn + ks * 32 + lg * 8;
            float4 x0 = *(const float4*)xp;
            float4 x1 = *(const float4*)(xp + 4);
            float xv[8] = {x0.x, x0.y, x0.z, x0.w, x1.x, x1.y, x1.z, x1.w};
            #pragma unroll
            for (int j = 0; j < 8; ++j) {
                ah[r][ks][j] = (_Float16)xv[j];
                s2 += xv[j] * xv[j];
            }
        }
        s2 += __shfl_xor(s2, 16);
        s2 += __shfl_xor(s2, 32);      // full ||x||^2 for row grow
        if (lg == 0) xn_s[w * RPW + r * 16 + lm] = s2;
    }
    #pragma unroll
    for (int i = 0; i < K / 256; ++i) wn2_s[tid + i * 256] = wn2[tid + i * 256];

    float m1[2][4], m2[2][4];
    int   i1[2][4];
    #pragma unroll
    for (int r = 0; r < 2; ++r)
        #pragma unroll
        for (int j = 0; j < 4; ++j) { m1[r][j] = -FLT_MAX; m2[r][j] = -FLT_MAX; i1[r][j] = 0; }

    asm volatile("s_waitcnt vmcnt(0)" ::: "memory");
    __syncthreads();                   // B1: pass-0 + wn2 + flagN=0 resident

    // ---- 8-pass scan: 4 B-tiles per pass, fold carries across passes ----
    for (int p = 0; p < NPASS; ++p) {
        const int cbase = p * KCH;
        #pragma unroll
        for (int t = 0; t < 4; ++t) {
            const int code_l = t * 16 + lm;            // slot within Wbuf
            const int code   = cbase + code_l;
            const float cinit = wn2_s[code];
            half8 bh[4];
            #pragma unroll
            for (int ks = 0; ks < 4; ++ks) {
                const int off = code_l * 256 + ((((ks << 2) + lg) ^ (code_l & 7)) << 4);
                bh[ks] = *(const half8*)(Wbuf + off);
            }
            f32x4 acc[2];
            #pragma unroll
            for (int r = 0; r < 2; ++r) acc[r] = (f32x4){cinit, cinit, cinit, cinit};
            #pragma unroll
            for (int ks = 0; ks < 4; ++ks) {
                #pragma unroll
                for (int r = 0; r < 2; ++r)
                    acc[r] = __builtin_amdgcn_mfma_f32_16x16x32_f16(ah[r][ks], bh[ks], acc[r], 0, 0, 0);
            }
            #pragma unroll
            for (int r = 0; r < 2; ++r) {
                #pragma unroll
                for (int j = 0; j < 4; ++j) {
                    const float a = acc[r][j];
                    m2[r][j] = __builtin_amdgcn_fmed3f(a, m1[r][j], m2[r][j]);
                    const bool gt = a > m1[r][j];
                    m1[r][j] = fmaxf(m1[r][j], a);
                    i1[r][j] = gt ? code : i1[r][j];
                }
            }
        }
        if (p + 1 < NPASS) {
            __syncthreads();           // all waves done reading this pass
            stage(p + 1);              // DMA next 16 KB over the same buffer
            asm volatile("s_waitcnt vmcnt(0)" ::: "memory");
            __syncthreads();           // next pass resident
        }
    }

    // ---- reduce (m1, idx, m2) across the 16 col-lanes (wave-local) ----
    #pragma unroll
    for (int sft = 1; sft < 16; sft <<= 1) {
        #pragma unroll
        for (int r = 0; r < 2; ++r) {
            #pragma unroll
            for (int j = 0; j < 4; ++j) {
                float o1 = __shfl_xor(m1[r][j], sft);
                float o2 = __shfl_xor(m2[r][j], sft);
                int   oi = __shfl_xor(i1[r][j], sft);
                if (o1 > m1[r][j] || (o1 == m1[r][j] && oi < i1[r][j])) {
                    m2[r][j] = fmaxf(m1[r][j], o2);
                    m1[r][j] = o1;
                    i1[r][j] = oi;
                } else {
                    m2[r][j] = fmaxf(m2[r][j], o1);
                }
            }
        }
    }

    float psum = 0.f;
    if (lm == 0) {
        #pragma unroll
        for (int r = 0; r < 2; ++r) {
            #pragma unroll
            for (int j = 0; j < 4; ++j) {
                const int row = w * RPW + r * 16 + lg * 4 + j;   // C row = lg*4 + reg
                sIdx[row] = i1[r][j];
                psum += xn_s[row] - 2.f * m1[r][j];              // dist^2 = ||x||^2 - 2a
                if (m1[r][j] - m2[r][j] < TAU_A) {
                    int pos = atomicAdd(&flagN, 1);
                    flagList[pos] = row;
                }
            }
        }
    }
    __syncthreads();                   // B2: sIdx + worklist complete

    // ---- exact refinement, block-distributed over the worklist ----
    {
        const int nf = flagN;
        const int cg    = lane >> 3;           // code subgroup 0..7
        const int dbase = (lane & 7) * 16;     // 16-dim slice per lane
        for (int fi = w; fi < nf; fi += WAVES) {
            const int rr = flagList[fi];
            const float* xp = Z + (row0 + rr) * Dn + dbase;
            double xd[16];
            #pragma unroll
            for (int q = 0; q < 16; q += 4) {
                float4 v = *(const float4*)(xp + q);
                xd[q] = v.x; xd[q+1] = v.y; xd[q+2] = v.z; xd[q+3] = v.w;
            }
            double best = 1e300; int bi = 0;
            for (int cb = 0; cb < 64; ++cb) {
                const int c = cb * 8 + cg;
                const float* wp = W + (size_t)c * Dn + dbase;
                double s = 0.0;
                #pragma unroll
                for (int q = 0; q < 16; q += 4) {
                    float4 wv = *(const float4*)(wp + q);
                    s += xd[q]   * (double)wv.x;
                    s += xd[q+1] * (double)wv.y;
                    s += xd[q+2] * (double)wv.z;
                    s += xd[q+3] * (double)wv.w;
                }
                s += __shfl_xor(s, 1);
                s += __shfl_xor(s, 2);
                s += __shfl_xor(s, 4);         // all 8 lanes of group hold dot(c)
                const double sc = wn64[c] - 2.0 * s;   // dist^2 - ||x||^2 (exact)
                if (sc < best) { best = sc; bi = c; } // ascending c => min-idx tiebreak
            }
            #pragma unroll
            for (int sft = 8; sft < 64; sft <<= 1) {
                double ob = __shfl_xor(best, sft);
                int    ok = __shfl_xor(bi, sft);
                if (ob < best || (ob == best && ok < bi)) { best = ob; bi = ok; }
            }
            if (lane == 0) sIdx[rr] = bi;
        }
    }
    __syncthreads();                   // B3: refined sIdx visible

    // ---- epilogue: gather W[ind], store z_q_st, ind, diff ----
    #pragma unroll
    for (int it = 0; it < 16; ++it) {
        int f4i = lane + it * 64;              // 0..1023
        int rl  = f4i >> 5, cq = f4i & 31;     // 32 rows x 32 float4
        int ind = sIdx[w * RPW + rl];
        float4 wv = ((const float4*)(W + (size_t)ind * Dn))[cq];
        ((float4*)(out + (row0 + w * RPW + rl) * Dn))[cq] = wv;
    }
    if (lane < RPW)
        out[IND_OFF + row0 + w * RPW + lane] = (float)sIdx[w * RPW + lane];

    #pragma unroll
    for (int sft = 1; sft < 64; sft <<= 1) psum += __shfl_xor(psum, sft);
    if (lane == 0) wpart[w] = psum;
    __syncthreads();
    if (tid == 0) {
        double t = 0.0;
        #pragma unroll
        for (int i = 0; i < WAVES; ++i) t += (double)wpart[i];
        atomicAdd(diffsum, t);
    }
}

__global__ void diff_kernel(const double* __restrict__ diffsum, float* __restrict__ out) {
    if (threadIdx.x == 0 && blockIdx.x == 0) {
        // KLD_SCALE * (COMMITMENT_COST + 1) * mean = 12.5 * mean
        out[DIFF_OFF] = (float)(12.5 * diffsum[0] / (double)ZQ_SIZE);
    }
}

extern "C" void kernel_launch(void* const* d_in, const int* in_sizes, int n_in,
                              void* d_out, int out_size, void* d_ws, size_t ws_size,
                              hipStream_t stream) {
    (void)in_sizes; (void)n_in; (void)out_size; (void)ws_size;
    const float* Z = (const float*)d_in[0];
    const float* W = (const float*)d_in[1];
    float* out = (float*)d_out;
    // ws: [0,8) diffsum; [64,2112) wn2 f32[512]; [2112,6208) wn64 f64[512];
    //     [8192, +128KB) Wp fp16 swizzled
    double* diffsum = (double*)d_ws;
    float*  wn2  = (float*)((char*)d_ws + 64);
    double* wn64 = (double*)((char*)d_ws + 2112);
    unsigned short* Wp = (unsigned short*)((char*)d_ws + 8192);

    hipMemsetAsync(d_ws, 0, 16, stream);
    prep_kernel<<<32, 256, 0, stream>>>(W, Wp, wn2, wn64);
    vq_main<<<NBLK, 256, 0, stream>>>(Z, W, Wp, wn2, wn64, out, diffsum);
    diff_kernel<<<1, 64, 0, stream>>>(diffsum, out);
}

// Round 13
// 134.813 us; speedup vs baseline: 2.2693x; 1.0081x over previous
//
#include <hip/hip_runtime.h>
#include <float.h>

// Quantize: z [8,4096,512] f32, embed_w [512,128] f32, GROUPS=4
// flat = z.reshape(131072,128); dist to 512 codes; argmin; gather; MSE scalar.
// d_out (f32): z_q_st [16777216], diff [1], ind [131072] (as float).
//
// r13 = two-kernel split of the r6 champion (102us):
//  - vq_scan: r6 structure (fp16-hi codebook 128KB resident in LDS, 16 waves
//    x 32 rows, MFMA scan, block-distributed EXACT fp64 refinement) but the
//    66MB gather/store epilogue is REMOVED -> writes only ind + diff partial.
//  - vq_gather: max-occupancy streaming kernel: reads ind, gathers W[ind]
//    (L2-resident), writes z_q_st at full bandwidth; last block writes diff.

typedef _Float16 half8 __attribute__((ext_vector_type(8)));
typedef __attribute__((ext_vector_type(4))) float f32x4;

constexpr int Dn = 128;
constexpr int K  = 512;
constexpr long long Mrows = 131072;
constexpr int RPW   = 32;                    // rows per wave
constexpr int WAVES = 16;                    // waves per block (1024 threads)
constexpr int RPB   = RPW * WAVES;           // 512 rows per block
constexpr int NBLK  = (int)(Mrows / RPB);    // 256
constexpr int GROWS = 64;                    // rows per gather block
constexpr int NGBLK = (int)(Mrows / GROWS);  // 2048
constexpr float TAU_A = 0.05f;               // score-margin for exact re-solve

constexpr size_t ZQ_SIZE  = (size_t)Mrows * Dn;
constexpr size_t DIFF_OFF = ZQ_SIZE;
constexpr size_t IND_OFF  = ZQ_SIZE + 1;

__device__ inline void gload_lds16(const void* g, void* l) {
    __builtin_amdgcn_global_load_lds(
        (const __attribute__((address_space(1))) unsigned int*)g,
        (__attribute__((address_space(3))) unsigned int*)l,
        16, 0, 0);
}

// W -> fp16 hi, XOR-swizzled granule order (granule g of code stored at slot
// g ^ (code&7)); also wn2 = -0.5*||w||^2 (f32) and wn64 = ||w||^2 (f64).
__global__ void prep_kernel(const float* __restrict__ W,
                            unsigned short* __restrict__ Wp,
                            float* __restrict__ wn2,
                            double* __restrict__ wn64) {
    int t = blockIdx.x * 256 + threadIdx.x;  // 0..8191 (512 codes * 16 granules)
    int code = t >> 4;
    int g    = t & 15;
    const float* src = W + (size_t)code * Dn + g * 8;
    float4 a = *(const float4*)src;
    float4 b = *(const float4*)(src + 4);
    float vv[8] = {a.x, a.y, a.z, a.w, b.x, b.y, b.z, b.w};
    half8 hv;
    double s2 = 0.0;
    #pragma unroll
    for (int j = 0; j < 8; ++j) {
        hv[j] = (_Float16)vv[j];
        s2 += (double)vv[j] * (double)vv[j];
    }
    *(half8*)((char*)Wp + (size_t)code * 256 + ((g ^ (code & 7)) << 4)) = hv;
    s2 += __shfl_xor(s2, 1);
    s2 += __shfl_xor(s2, 2);
    s2 += __shfl_xor(s2, 4);
    s2 += __shfl_xor(s2, 8);
    if (g == 0) {
        wn2[code]  = (float)(-0.5 * s2);
        wn64[code] = s2;
    }
}

__global__ __launch_bounds__(1024, 4) void vq_scan(
        const float* __restrict__ Z, const float* __restrict__ W,
        const unsigned short* __restrict__ Wp, const float* __restrict__ wn2,
        const double* __restrict__ wn64,
        float* __restrict__ out, double* __restrict__ diffsum) {
    __shared__ __align__(16) char Wlds[131072];   // full codebook, fp16 hi, swizzled
    __shared__ float wn2_s[K];
    __shared__ float xn_s[RPB];
    __shared__ int   sIdx[RPB];
    __shared__ int   flagList[RPB];
    __shared__ int   flagN;
    __shared__ float wpart[WAVES];

    const int tid  = threadIdx.x;
    const int w    = tid >> 6;
    const int lane = tid & 63;
    const int lm   = lane & 15;        // A row / B col within 16-tile
    const int lg   = lane >> 4;        // k-block (0..3)
    const size_t row0 = (size_t)blockIdx.x * RPB;

    if (tid == 0) flagN = 0;

    // ---- codebook DMA: 128 KB once, linear dest (pre-swizzled src) ----
    {
        const char* gsrc = (const char*)Wp;
        #pragma unroll
        for (int it = 0; it < 8; ++it) {
            const int gbase = it * 1024 + w * 64;            // wave-uniform base
            gload_lds16(gsrc + (size_t)(gbase + lane) * 16, Wlds + (size_t)gbase * 16);
        }
    }
    if (tid < K) wn2_s[tid] = wn2[tid];

    // ---- X fragments (fp16) + exact row norms (overlap the DMA) ----
    half8 ah[2][4];                     // [16-row tile][ks]
    #pragma unroll
    for (int r = 0; r < 2; ++r) {
        const size_t grow = row0 + (size_t)w * RPW + r * 16 + lm;
        float s2 = 0.f;
        #pragma unroll
        for (int ks = 0; ks < 4; ++ks) {
            const float* xp = Z + grow * Dn + ks * 32 + lg * 8;
            float4 x0 = *(const float4*)xp;
            float4 x1 = *(const float4*)(xp + 4);
            float xv[8] = {x0.x, x0.y, x0.z, x0.w, x1.x, x1.y, x1.z, x1.w};
            #pragma unroll
            for (int j = 0; j < 8; ++j) {
                ah[r][ks][j] = (_Float16)xv[j];
                s2 += xv[j] * xv[j];
            }
        }
        s2 += __shfl_xor(s2, 16);
        s2 += __shfl_xor(s2, 32);      // full ||x||^2 for row grow
        if (lg == 0) xn_s[w * RPW + r * 16 + lm] = s2;
    }

    float m1[2][4], m2[2][4];
    int   i1[2][4];
    #pragma unroll
    for (int r = 0; r < 2; ++r)
        #pragma unroll
        for (int j = 0; j < 4; ++j) { m1[r][j] = -FLT_MAX; m2[r][j] = -FLT_MAX; i1[r][j] = 0; }

    asm volatile("s_waitcnt vmcnt(0)" ::: "memory");
    __syncthreads();                   // B1: codebook + wn2 + flagN resident

    // ---- main scan: 32 B-tiles x (2 A-tiles x 4 k-steps), no syncs ----
    #pragma unroll 2
    for (int t = 0; t < 32; ++t) {
        const int code = t * 16 + lm;
        const float cinit = wn2_s[code];
        half8 bh[4];
        #pragma unroll
        for (int ks = 0; ks < 4; ++ks) {
            const int off = code * 256 + ((((ks << 2) + lg) ^ (code & 7)) << 4);
            bh[ks] = *(const half8*)(Wlds + off);
        }
        f32x4 acc[2];
        #pragma unroll
        for (int r = 0; r < 2; ++r) acc[r] = (f32x4){cinit, cinit, cinit, cinit};
        #pragma unroll
        for (int ks = 0; ks < 4; ++ks) {
            #pragma unroll
            for (int r = 0; r < 2; ++r)
                acc[r] = __builtin_amdgcn_mfma_f32_16x16x32_f16(ah[r][ks], bh[ks], acc[r], 0, 0, 0);
        }
        #pragma unroll
        for (int r = 0; r < 2; ++r) {
            #pragma unroll
            for (int j = 0; j < 4; ++j) {
                const float a = acc[r][j];
                m2[r][j] = __builtin_amdgcn_fmed3f(a, m1[r][j], m2[r][j]);
                const bool gt = a > m1[r][j];
                m1[r][j] = fmaxf(m1[r][j], a);
                i1[r][j] = gt ? code : i1[r][j];
            }
        }
    }

    // ---- reduce (m1, idx, m2) across the 16 col-lanes ----
    #pragma unroll
    for (int sft = 1; sft < 16; sft <<= 1) {
        #pragma unroll
        for (int r = 0; r < 2; ++r) {
            #pragma unroll
            for (int j = 0; j < 4; ++j) {
                float o1 = __shfl_xor(m1[r][j], sft);
                float o2 = __shfl_xor(m2[r][j], sft);
                int   oi = __shfl_xor(i1[r][j], sft);
                if (o1 > m1[r][j] || (o1 == m1[r][j] && oi < i1[r][j])) {
                    m2[r][j] = fmaxf(m1[r][j], o2);
                    m1[r][j] = o1;
                    i1[r][j] = oi;
                } else {
                    m2[r][j] = fmaxf(m2[r][j], o1);
                }
            }
        }
    }

    float psum = 0.f;
    if (lm == 0) {
        #pragma unroll
        for (int r = 0; r < 2; ++r) {
            #pragma unroll
            for (int j = 0; j < 4; ++j) {
                const int row = w * RPW + r * 16 + lg * 4 + j;   // C row = lg*4 + reg
                sIdx[row] = i1[r][j];
                psum += xn_s[row] - 2.f * m1[r][j];              // dist^2 = ||x||^2 - 2a
                if (m1[r][j] - m2[r][j] < TAU_A) {
                    int pos = atomicAdd(&flagN, 1);
                    flagList[pos] = row;
                }
            }
        }
    }
    __syncthreads();                   // B2: sIdx + worklist complete

    // ---- exact refinement, block-distributed over the worklist ----
    {
        const int nf = flagN;
        const int cg    = lane >> 3;           // code subgroup 0..7
        const int dbase = (lane & 7) * 16;     // 16-dim slice per lane
        for (int fi = w; fi < nf; fi += WAVES) {
            const int rr = flagList[fi];
            const float* xp = Z + (row0 + rr) * Dn + dbase;
            double xd[16];
            #pragma unroll
            for (int q = 0; q < 16; q += 4) {
                float4 v = *(const float4*)(xp + q);
                xd[q] = v.x; xd[q+1] = v.y; xd[q+2] = v.z; xd[q+3] = v.w;
            }
            double best = 1e300; int bi = 0;
            for (int cb = 0; cb < 64; ++cb) {
                const int c = cb * 8 + cg;
                const float* wp = W + (size_t)c * Dn + dbase;
                double s = 0.0;
                #pragma unroll
                for (int q = 0; q < 16; q += 4) {
                    float4 wv = *(const float4*)(wp + q);
                    s += xd[q]   * (double)wv.x;
                    s += xd[q+1] * (double)wv.y;
                    s += xd[q+2] * (double)wv.z;
                    s += xd[q+3] * (double)wv.w;
                }
                s += __shfl_xor(s, 1);
                s += __shfl_xor(s, 2);
                s += __shfl_xor(s, 4);         // all 8 lanes of group hold dot(c)
                const double sc = wn64[c] - 2.0 * s;   // dist^2 - ||x||^2 (exact)
                if (sc < best) { best = sc; bi = c; } // ascending c => min-idx tiebreak
            }
            #pragma unroll
            for (int sft = 8; sft < 64; sft <<= 1) {
                double ob = __shfl_xor(best, sft);
                int    ok = __shfl_xor(bi, sft);
                if (ob < best || (ob == best && ok < bi)) { best = ob; bi = ok; }
            }
            if (lane == 0) sIdx[rr] = bi;
        }
    }
    __syncthreads();                   // B3: refined sIdx visible

    // ---- tail: write ind (as float) + diff partial; NO z_q_st store here ----
    if (tid < RPB) out[IND_OFF + row0 + tid] = (float)sIdx[tid];

    #pragma unroll
    for (int sft = 1; sft < 64; sft <<= 1) psum += __shfl_xor(psum, sft);
    if (lane == 0) wpart[w] = psum;
    __syncthreads();
    if (tid == 0) {
        double t = 0.0;
        #pragma unroll
        for (int i = 0; i < WAVES; ++i) t += (double)wpart[i];
        atomicAdd(diffsum, t);
    }
}

// Max-occupancy streaming gather: z_q_st[row] = W[ind[row]]; last block
// finalizes diff. Reads ind from the out buffer (written by vq_scan).
__global__ __launch_bounds__(256) void vq_gather(
        const float* __restrict__ W, float* __restrict__ out,
        const double* __restrict__ diffsum, unsigned int* __restrict__ done) {
    __shared__ int inds[GROWS];
    const int tid = threadIdx.x;
    const size_t row0 = (size_t)blockIdx.x * GROWS;
    if (tid < GROWS) inds[tid] = (int)out[IND_OFF + row0 + tid];
    __syncthreads();
    #pragma unroll
    for (int it = 0; it < 8; ++it) {
        int f4i = tid + it * 256;              // 0..2047 = 64 rows x 32 float4
        int rl  = f4i >> 5, cq = f4i & 31;
        int ind = inds[rl];
        float4 wv = ((const float4*)(W + (size_t)ind * Dn))[cq];
        ((float4*)(out + (row0 + rl) * Dn))[cq] = wv;
    }
    if (tid == 0) {
        unsigned int old = atomicAdd(done, 1u);
        if (old == (unsigned int)(NGBLK - 1)) {
            // all scan-kernel diff partials landed before this kernel launched
            out[DIFF_OFF] = (float)(12.5 * diffsum[0] / (double)ZQ_SIZE);
        }
    }
}

extern "C" void kernel_launch(void* const* d_in, const int* in_sizes, int n_in,
                              void* d_out, int out_size, void* d_ws, size_t ws_size,
                              hipStream_t stream) {
    (void)in_sizes; (void)n_in; (void)out_size; (void)ws_size;
    const float* Z = (const float*)d_in[0];
    const float* W = (const float*)d_in[1];
    float* out = (float*)d_out;
    // ws: [0,8) diffsum f64; [8,12) done u32; [64,2112) wn2 f32[512];
    //     [2112,6208) wn64 f64[512]; [8192, +128KB) Wp fp16 swizzled
    double* diffsum = (double*)d_ws;
    unsigned int* done = (unsigned int*)((char*)d_ws + 8);
    float*  wn2  = (float*)((char*)d_ws + 64);
    double* wn64 = (double*)((char*)d_ws + 2112);
    unsigned short* Wp = (unsigned short*)((char*)d_ws + 8192);

    hipMemsetAsync(d_ws, 0, 16, stream);   // zero diffsum + done each call
    prep_kernel<<<32, 256, 0, stream>>>(W, Wp, wn2, wn64);
    vq_scan<<<NBLK, 1024, 0, stream>>>(Z, W, Wp, wn2, wn64, out, diffsum);
    vq_gather<<<NGBLK, 256, 0, stream>>>(W, out, diffsum, done);
}